// Round 3
// baseline (930.174 us; speedup 1.0000x reference)
//
#include <hip/hip_runtime.h>
#include <hip/hip_bf16.h>

// ---------------- problem constants ----------------
#define BATCH   256
#define NTOK    50          // 49 patches + CLS
#define NPATCH  49
#define HID     256
#define HEADS   8
#define DH      32
#define NBLK    4
#define MLPD    1024
#define OUTD    1000
#define KPATCH  3072        // 3*32*32
#define MROWS   (BATCH*NTOK)     // 12800
#define MPATCH  (BATCH*NPATCH)   // 12544
#define MAXDEG  12               // max in-degree for t>=1 (8-neigh + self)

typedef __attribute__((ext_vector_type(4))) float  floatx4;
typedef __attribute__((ext_vector_type(8))) __bf16 bf16x8;
typedef __attribute__((ext_vector_type(4))) int    int4v;
typedef __attribute__((ext_vector_type(4))) short  short4v;

// Runtime input-dtype detection: ln1_g is all-ones. First 16-bit word is
// 0x3F80 iff the float inputs are bf16; fp32 gives 0x0000 (low mantissa).
// (Round-2 FETCH_SIZE ~154MB == fp32 images => this problem variant is fp32.)
__device__ __forceinline__ bool tag_is_bf16(const unsigned short* tag) {
    return tag[0] == 0x3F80u;
}
__device__ __forceinline__ float ldf(const void* p, long i, bool bf) {
    return bf ? __bfloat162float(((const __hip_bfloat16*)p)[i])
              : ((const float*)p)[i];
}

// packed small-param layout (bf16 canonical), offsets in elements
#define OFF_BMAP 0
#define OFF_CLS  256
#define OFF_ASRC 512
#define OFF_ADST 1536
#define OFF_BGAT 2560
#define OFF_LN1G 3584
#define OFF_LN1B 4608
#define OFF_LN2G 5632
#define OFF_LN2B 6656
#define OFF_B1   7680
#define OFF_B2   11776
#define OFF_BOUT 12800
#define SP_TOTAL 13800

struct SmallSrc {
    const void *bmap, *cls, *asrc, *adst, *bgat, *ln1g, *ln1b, *ln2g, *ln2b, *b1, *b2, *bout;
};

__global__ void pack_params(SmallSrc s, const unsigned short* tag,
                            __hip_bfloat16* __restrict__ sp) {
    bool bf = tag_is_bf16(tag);
    int idx = blockIdx.x * 256 + threadIdx.x;
    if (idx >= SP_TOTAL) return;
    const void* src; long off;
    if      (idx < OFF_CLS)  { src = s.bmap; off = idx; }
    else if (idx < OFF_ASRC) { src = s.cls;  off = idx - OFF_CLS; }
    else if (idx < OFF_ADST) { src = s.asrc; off = idx - OFF_ASRC; }
    else if (idx < OFF_BGAT) { src = s.adst; off = idx - OFF_ADST; }
    else if (idx < OFF_LN1G) { src = s.bgat; off = idx - OFF_BGAT; }
    else if (idx < OFF_LN1B) { src = s.ln1g; off = idx - OFF_LN1G; }
    else if (idx < OFF_LN2G) { src = s.ln1b; off = idx - OFF_LN1B; }
    else if (idx < OFF_LN2B) { src = s.ln2g; off = idx - OFF_LN2G; }
    else if (idx < OFF_B1)   { src = s.ln2b; off = idx - OFF_LN2B; }
    else if (idx < OFF_B2)   { src = s.b1;   off = idx - OFF_B1; }
    else if (idx < OFF_BOUT) { src = s.b2;   off = idx - OFF_B2; }
    else                     { src = s.bout; off = idx - OFF_BOUT; }
    sp[idx] = __float2bfloat16(ldf(src, off, bf));
}

// =====================================================================
// prep: block 0 builds dense adjacency (counts + self loops) AND the
// per-target sparse neighbor lists; blocks 1..50 build the pos-emb table.
// =====================================================================
__global__ void prep_kernel(const int* __restrict__ ei, int E0,
                            float* __restrict__ adj, float* __restrict__ pe,
                            int* __restrict__ nbrI, float* __restrict__ nbrW,
                            int* __restrict__ deg) {
    int tid = threadIdx.x;
    if (blockIdx.x == 0) {
        for (int i = tid; i < NTOK * NTOK; i += 64) adj[i] = 0.f;
        __syncthreads();
        bool is64 = (ei[1] == 0);   // int64 little-endian high word
        for (int e = tid; e < E0; e += 64) {
            int s, d;
            if (is64) { s = ei[2 * e]; d = ei[2 * (E0 + e)]; }
            else      { s = ei[e];     d = ei[E0 + e]; }
            if ((unsigned)s < NTOK && (unsigned)d < NTOK)
                atomicAdd(&adj[d * NTOK + s], 1.f);
        }
        if (tid < NTOK) atomicAdd(&adj[tid * NTOK + tid], 1.f);  // self loops
        __syncthreads();
        if (tid > 0 && tid < NTOK) {            // t>=1 sparse in-lists
            int d = 0;
            for (int s = 0; s < NTOK; ++s) {
                float c = adj[tid * NTOK + s];
                if (c > 0.f && d < MAXDEG) { nbrI[tid * MAXDEG + d] = s;
                                             nbrW[tid * MAXDEG + d] = c; ++d; }
            }
            deg[tid] = d;
        }
        if (tid == 0) deg[0] = 0;               // t=0 handled full-width
    } else {
        int t = blockIdx.x - 1;
        for (int j = tid; j < HID; j += 64) {
            float jeff = (float)(j & ~1);
            float ang = (float)t / powf(10000.f, jeff / (float)HID);
            pe[t * HID + j] = ((j & 1) == 0) ? sinf(ang) : cosf(ang);
        }
    }
}

// =====================================================================
// LDS-tiled transpose of all weights to [N][K] canonical bf16.
// 64x64 tiles, coalesced reads AND writes. 832 blocks total.
// =====================================================================
__global__ __launch_bounds__(256) void transpose2(
    const void* __restrict__ Wmap, const void* __restrict__ Wgat,
    const void* __restrict__ W1,   const void* __restrict__ W2,
    const void* __restrict__ Wout, const unsigned short* tag,
    __hip_bfloat16* __restrict__ wmapT, __hip_bfloat16* __restrict__ wgatT,
    __hip_bfloat16* __restrict__ w1T,   __hip_bfloat16* __restrict__ w2T,
    __hip_bfloat16* __restrict__ woutT) {
    __shared__ __hip_bfloat16 tl[64][65];
    bool bf = tag_is_bf16(tag);
    int b = blockIdx.x;
    const void* src; __hip_bfloat16* dst; int R, C, tR; long so, dofs;
    if (b < 192)      { src = Wmap; dst = wmapT; R = 3072; C = 256;  tR = 48;
                        so = 0; dofs = 0; }
    else if (b < 256) { int ti = b - 192, l = ti >> 4; b = ti & 15;
                        src = Wgat; dst = wgatT; R = 256; C = 256; tR = 4;
                        so = (long)l * 65536; dofs = so; goto tiled; }
    else if (b < 512) { int ti = b - 256, l = ti >> 6; b = ti & 63;
                        src = W1; dst = w1T; R = 256; C = 1024; tR = 4;
                        so = (long)l * 262144; dofs = so; goto tiled; }
    else if (b < 768) { int ti = b - 512, l = ti >> 6; b = ti & 63;
                        src = W2; dst = w2T; R = 1024; C = 256; tR = 16;
                        so = (long)l * 262144; dofs = so; goto tiled; }
    else              { b -= 768; src = Wout; dst = woutT; R = 256; C = 1000;
                        tR = 4; so = 0; dofs = 0; }
tiled:
    int r0 = (b % tR) * 64, c0 = (b / tR) * 64;
    int tx = threadIdx.x & 63, ty = threadIdx.x >> 6;
#pragma unroll
    for (int j = 0; j < 16; ++j) {
        int rr = ty + 4 * j;
        float v = (c0 + tx < C) ? ldf(src, so + (long)(r0 + rr) * C + c0 + tx, bf) : 0.f;
        tl[rr][tx] = __float2bfloat16(v);
    }
    __syncthreads();
#pragma unroll
    for (int j = 0; j < 16; ++j) {
        int i2 = ty + 4 * j;
        if (c0 + i2 < C)
            dst[dofs + (long)(c0 + i2) * R + r0 + tx] = tl[tx][i2];
    }
}

// =====================================================================
// init resid with bias + positional emb (+ cls row). Runs BEFORE the
// split-K patch GEMM which atomically accumulates into it.
// =====================================================================
__global__ void init_resid(const __hip_bfloat16* __restrict__ sp,
                           const float* __restrict__ pe, float* __restrict__ resid) {
    int idx = blockIdx.x * 256 + threadIdx.x;   // MROWS*HID
    int row = idx >> 8, c = idx & 255, t = row % NTOK;
    resid[idx] = (t == 0) ? __bfloat162float(sp[OFF_CLS + c]) + pe[c]
                          : __bfloat162float(sp[OFF_BMAP + c]) + pe[t * HID + c];
}

// =====================================================================
// 128x128 MFMA GEMM: C[M,N] = A[M,K] * BT[N,K]^T  (bf16 in, fp32 acc)
// 4 waves in 2x2, each wave 64x64 (4x4 of 16x16x32 MFMA). BK=32.
// Unpadded LDS [128][32]: write & fragment-read patterns are perfect 1KB
// permutations -> 0 bank conflicts. Register-prefetch pipeline.
// MODE 0: outF=acc; 1: outF=acc+bias; 2: outB=bf16(gelu(acc+bias));
// MODE 3: outF+=acc+bias.  M%128==0, K%32==0 always; col guard for N.
// =====================================================================
template<int MODE>
__global__ __launch_bounds__(256) void gemm128(
    const __hip_bfloat16* __restrict__ A, const __hip_bfloat16* __restrict__ BT,
    const __hip_bfloat16* __restrict__ bias,
    float* __restrict__ outF, __hip_bfloat16* __restrict__ outB,
    int M, int N, int K) {
    __shared__ short As[128][32];
    __shared__ short Bs[128][32];
    int tid = threadIdx.x;
    int m0 = blockIdx.x * 128, n0 = blockIdx.y * 128;
    int lr = tid >> 2, lc = (tid & 3) * 8;
    int lane = tid & 63, wave = tid >> 6;
    int wm = (wave >> 1) * 64, wn = (wave & 1) * 64;
    int q = lane >> 4, r = lane & 15, q8 = q * 8;
    const short* Ag = (const short*)A;
    const short* Bg = (const short*)BT;
    long a0 = (long)(m0 + lr) * K + lc, a1 = a0 + (long)64 * K;
    int bn0 = n0 + lr, bn1 = bn0 + 64;
    long b0 = (long)bn0 * K + lc, b1 = (long)bn1 * K + lc;
    bool v0 = bn0 < N, v1 = bn1 < N;
    floatx4 acc[4][4];
#pragma unroll
    for (int i = 0; i < 4; ++i)
#pragma unroll
        for (int j = 0; j < 4; ++j) acc[i][j] = floatx4{0.f, 0.f, 0.f, 0.f};
    int4v za = {0, 0, 0, 0};
    int4v avA = *(const int4v*)(Ag + a0), avB = *(const int4v*)(Ag + a1);
    int4v bvA = v0 ? *(const int4v*)(Bg + b0) : za;
    int4v bvB = v1 ? *(const int4v*)(Bg + b1) : za;
    int nk = K >> 5;
    for (int kt = 0; kt < nk; ++kt) {
        __syncthreads();
        *(int4v*)&As[lr][lc] = avA; *(int4v*)&As[64 + lr][lc] = avB;
        *(int4v*)&Bs[lr][lc] = bvA; *(int4v*)&Bs[64 + lr][lc] = bvB;
        __syncthreads();
        if (kt + 1 < nk) {
            long o = (long)(kt + 1) * 32;
            avA = *(const int4v*)(Ag + a0 + o); avB = *(const int4v*)(Ag + a1 + o);
            bvA = v0 ? *(const int4v*)(Bg + b0 + o) : za;
            bvB = v1 ? *(const int4v*)(Bg + b1 + o) : za;
        }
        bf16x8 af[4], bfv[4];
#pragma unroll
        for (int i = 0; i < 4; ++i) af[i]  = *(const bf16x8*)&As[wm + 16 * i + r][q8];
#pragma unroll
        for (int j = 0; j < 4; ++j) bfv[j] = *(const bf16x8*)&Bs[wn + 16 * j + r][q8];
#pragma unroll
        for (int i = 0; i < 4; ++i)
#pragma unroll
            for (int j = 0; j < 4; ++j)
                acc[i][j] = __builtin_amdgcn_mfma_f32_16x16x32_bf16(af[i], bfv[j], acc[i][j], 0, 0, 0);
    }
    // epilogue: C/D layout col = lane&15, row = quad*4 + reg  [m89-verified]
#pragma unroll
    for (int j = 0; j < 4; ++j) {
        int col = n0 + wn + 16 * j + r;
        if (col >= N) continue;
        float bv = (MODE != 0) ? __bfloat162float(bias[col]) : 0.f;
#pragma unroll
        for (int i = 0; i < 4; ++i) {
#pragma unroll
            for (int reg = 0; reg < 4; ++reg) {
                int row = m0 + wm + 16 * i + q * 4 + reg;
                float v = acc[i][j][reg];
                long oi = (long)row * N + col;
                if (MODE == 0) outF[oi] = v;
                if (MODE == 1) outF[oi] = v + bv;
                if (MODE == 2) {
                    float u = v + bv;
                    float g = 0.5f * u * (1.f + erff(u * 0.70710678118654752f));
                    outB[oi] = __float2bfloat16(g);
                }
                if (MODE == 3) outF[oi] += v + bv;
            }
        }
    }
}

// =====================================================================
// Patch-embed GEMM, 128x128 tile + split-K (4 chunks of 768).
// Patchify fused in the A loader (dtype-branched). AtomicAdds into resid
// (pre-initialized with bias+pe by init_resid).
// =====================================================================
__global__ __launch_bounds__(256) void patch_gemm128(
    const void* __restrict__ img, const __hip_bfloat16* __restrict__ wmapT,
    const unsigned short* tag, float* __restrict__ resid) {
    __shared__ short As[128][32];
    __shared__ short Bs[128][32];
    bool bf = tag_is_bf16(tag);
    int tid = threadIdx.x;
    int m0 = blockIdx.x * 128, n0 = blockIdx.y * 128, kc = blockIdx.z;
    int lr = tid >> 2, lc = (tid & 3) * 8;
    int lane = tid & 63, wave = tid >> 6;
    int wm = (wave >> 1) * 64, wn = (wave & 1) * 64;
    int q = lane >> 4, r = lane & 15, q8 = q * 8;
    int mA = m0 + lr, mB = mA + 64;
    long baseA, baseB;
    { int pb = mA / 49, pp = mA % 49; baseA = (long)pb * 150528 + (pp / 7) * 7168 + (pp % 7) * 32; }
    { int pb = mB / 49, pp = mB % 49; baseB = (long)pb * 150528 + (pp / 7) * 7168 + (pp % 7) * 32; }
    const short* Bg = (const short*)wmapT;
    long b0 = (long)(n0 + lr) * KPATCH + kc * 768 + lc;
    long b1 = b0 + (long)64 * KPATCH;
    floatx4 acc[4][4];
#pragma unroll
    for (int i = 0; i < 4; ++i)
#pragma unroll
        for (int j = 0; j < 4; ++j) acc[i][j] = floatx4{0.f, 0.f, 0.f, 0.f};
    auto loadA = [&](long base, int ku) -> bf16x8 {
        long gofs = base + (ku >> 5) * 50176 + (ku & 31) * 224 + lc;
        if (bf) return *(const bf16x8*)(((const __bf16*)img) + gofs);
        const float* f = (const float*)img;
        floatx4 f0 = *(const floatx4*)(f + gofs);
        floatx4 f1 = *(const floatx4*)(f + gofs + 4);
        union { bf16x8 v; __hip_bfloat16 h[8]; } u;
#pragma unroll
        for (int j = 0; j < 4; ++j) { u.h[j] = __float2bfloat16(f0[j]);
                                      u.h[4 + j] = __float2bfloat16(f1[j]); }
        return u.v;
    };
    int ku0 = kc * 24;
    bf16x8 avA = loadA(baseA, ku0), avB = loadA(baseB, ku0);
    int4v bvA = *(const int4v*)(Bg + b0), bvB = *(const int4v*)(Bg + b1);
    for (int kt = 0; kt < 24; ++kt) {
        __syncthreads();
        *(bf16x8*)&As[lr][lc] = avA; *(bf16x8*)&As[64 + lr][lc] = avB;
        *(int4v*)&Bs[lr][lc] = bvA;  *(int4v*)&Bs[64 + lr][lc] = bvB;
        __syncthreads();
        if (kt < 23) {
            avA = loadA(baseA, ku0 + kt + 1); avB = loadA(baseB, ku0 + kt + 1);
            long o = (long)(kt + 1) * 32;
            bvA = *(const int4v*)(Bg + b0 + o); bvB = *(const int4v*)(Bg + b1 + o);
        }
        bf16x8 af[4], bfv[4];
#pragma unroll
        for (int i = 0; i < 4; ++i) af[i]  = *(const bf16x8*)&As[wm + 16 * i + r][q8];
#pragma unroll
        for (int j = 0; j < 4; ++j) bfv[j] = *(const bf16x8*)&Bs[wn + 16 * j + r][q8];
#pragma unroll
        for (int i = 0; i < 4; ++i)
#pragma unroll
            for (int j = 0; j < 4; ++j)
                acc[i][j] = __builtin_amdgcn_mfma_f32_16x16x32_bf16(af[i], bfv[j], acc[i][j], 0, 0, 0);
    }
#pragma unroll
    for (int j = 0; j < 4; ++j) {
        int col = n0 + wn + 16 * j + r;    // always < 256
#pragma unroll
        for (int i = 0; i < 4; ++i) {
#pragma unroll
            for (int reg = 0; reg < 4; ++reg) {
                int row = m0 + wm + 16 * i + q * 4 + reg;
                int bb = row / 49, pp = row % 49;
                atomicAdd(&resid[((long)bb * NTOK + pp + 1) * HID + col], acc[i][j][reg]);
            }
        }
    }
}

// =====================================================================
// LayerNorm: one wave per row, float4 loads, fp32 in -> bf16 out
// =====================================================================
__global__ __launch_bounds__(256) void ln_kernel(
    const float* __restrict__ x, const __hip_bfloat16* __restrict__ g,
    const __hip_bfloat16* __restrict__ bta, __hip_bfloat16* __restrict__ y) {
    int row = blockIdx.x * 4 + (threadIdx.x >> 6);
    int lane = threadIdx.x & 63;
    floatx4 v = ((const floatx4*)(x + (long)row * HID))[lane];
    float s = v[0] + v[1] + v[2] + v[3];
#pragma unroll
    for (int off = 32; off; off >>= 1) s += __shfl_xor(s, off, 64);
    float mu = s * (1.f / HID);
    float d2 = 0.f;
#pragma unroll
    for (int i = 0; i < 4; ++i) { float d = v[i] - mu; d2 += d * d; }
#pragma unroll
    for (int off = 32; off; off >>= 1) d2 += __shfl_xor(d2, off, 64);
    float rstd = rsqrtf(d2 * (1.f / HID) + 1e-5f);
    union { short4v s4; __hip_bfloat16 h[4]; } o;
#pragma unroll
    for (int i = 0; i < 4; ++i) {
        int c = lane * 4 + i;
        float t = (v[i] - mu) * rstd * __bfloat162float(g[c]) + __bfloat162float(bta[c]);
        o.h[i] = __float2bfloat16(t);
    }
    ((short4v*)(y + (long)row * HID))[lane] = o.s4;
}

// =====================================================================
// GAT v2: one block per batch. Phase 1: stage h + compute per-node logits.
// Phase 2: all (t,head) alphas in parallel (sparse lists, t=0 full-width).
// Phase 3: barrier-free sparse aggregation, resid += out + bias.
// =====================================================================
__global__ __launch_bounds__(256) void gat_kernel2(
    const float* __restrict__ h, const float* __restrict__ adj,
    const int* __restrict__ nbrI, const float* __restrict__ nbrW,
    const int* __restrict__ deg,
    const __hip_bfloat16* __restrict__ sp, int l, float* __restrict__ resid) {
    __shared__ float hs[NTOK][HID];                 // 50 KB
    __shared__ float als[NTOK][HEADS], ald[NTOK][HEADS];
    __shared__ float alpha0[HEADS][NTOK];           // t=0 (CLS): full 50 sources
    __shared__ float alphaC[HEADS][NTOK][MAXDEG];   // t>=1 compact: 19.2 KB
    __shared__ float attS[HID], attD[HID], bg[HID];
    __shared__ int   nI[NTOK][MAXDEG];
    __shared__ int   dgs[NTOK];
    int b = blockIdx.x, tid = threadIdx.x;
    const float* hb = h + (long)b * (NTOK * HID);
    for (int i = tid; i < NTOK * HID / 4; i += 256)
        ((floatx4*)hs)[i] = ((const floatx4*)hb)[i];
    attS[tid] = __bfloat162float(sp[OFF_ASRC + l * HID + tid]);
    attD[tid] = __bfloat162float(sp[OFF_ADST + l * HID + tid]);
    bg[tid]   = __bfloat162float(sp[OFF_BGAT + l * HID + tid]);
    for (int i = tid; i < NTOK * MAXDEG; i += 256) ((int*)nI)[i] = nbrI[i];
    if (tid < NTOK) dgs[tid] = deg[tid];
    __syncthreads();
    for (int pr = tid; pr < NTOK * HEADS; pr += 256) {   // node logits
        int s = pr >> 3, hh = pr & 7;
        float a1 = 0.f, a2 = 0.f;
#pragma unroll
        for (int d = 0; d < DH; ++d) {
            float hv = hs[s][hh * DH + d];
            a1 += hv * attS[hh * DH + d];
            a2 += hv * attD[hh * DH + d];
        }
        als[s][hh] = a1; ald[s][hh] = a2;
    }
    __syncthreads();
    for (int pr = tid; pr < NTOK * HEADS; pr += 256) {   // edge softmax
        int t = pr >> 3, hh = pr & 7;
        float aldt = ald[t][hh];
        if (t == 0) {
            float mx = -1e30f;
            for (int s = 0; s < NTOK; ++s) {
                float w = adj[s];                        // row 0 of adj
                if (w > 0.f) {
                    float e = als[s][hh] + aldt; e = (e > 0.f) ? e : 0.2f * e;
                    mx = fmaxf(mx, e);
                }
            }
            float sum = 0.f;
            for (int s = 0; s < NTOK; ++s) {
                float w = adj[s], v = 0.f;
                if (w > 0.f) {
                    float e = als[s][hh] + aldt; e = (e > 0.f) ? e : 0.2f * e;
                    v = w * expf(e - mx);
                }
                alpha0[hh][s] = v; sum += v;
            }
            float inv = 1.f / (sum + 1e-16f);
            for (int s = 0; s < NTOK; ++s) alpha0[hh][s] *= inv;
        } else {
            int d = dgs[t];
            float mx = -1e30f;
            for (int j = 0; j < d; ++j) {
                float e = als[nI[t][j]][hh] + aldt; e = (e > 0.f) ? e : 0.2f * e;
                mx = fmaxf(mx, e);
            }
            float sum = 0.f;
            for (int j = 0; j < d; ++j) {
                float e = als[nI[t][j]][hh] + aldt; e = (e > 0.f) ? e : 0.2f * e;
                float w = nbrW[t * MAXDEG + j] * expf(e - mx);
                alphaC[hh][t][j] = w; sum += w;
            }
            float inv = 1.f / (sum + 1e-16f);
            for (int j = 0; j < d; ++j) alphaC[hh][t][j] *= inv;
        }
    }
    __syncthreads();
    int hd = tid >> 5, ln32 = tid & 31, col = hd * DH + ln32;
    float* res = resid + (long)b * (NTOK * HID);
    float bgc = bg[col];
    {
        float acc = 0.f;
        for (int s = 0; s < NTOK; ++s) acc += alpha0[hd][s] * hs[s][col];
        res[col] += acc + bgc;
    }
    for (int t = 1; t < NTOK; ++t) {
        float acc = 0.f; int d = dgs[t];
        for (int j = 0; j < d; ++j) acc += alphaC[hd][t][j] * hs[nI[t][j]][col];
        res[t * HID + col] += acc + bgc;
    }
}

// =====================================================================
__global__ void extract_cls(const float* __restrict__ resid, __hip_bfloat16* __restrict__ xb) {
    int idx = blockIdx.x * 256 + threadIdx.x;   // < 256*256
    int b = idx >> 8, n = idx & 255;
    xb[idx] = __float2bfloat16(resid[(long)b * (NTOK * HID) + n]);
}

__global__ __launch_bounds__(256) void softmax_kernel(
    const float* __restrict__ logits, const unsigned short* tag, void* __restrict__ out) {
    __shared__ float red[8];
    bool bf = tag_is_bf16(tag);
    int b = blockIdx.x, tid = threadIdx.x;
    const float* Lr = logits + (long)b * OUTD;
    float v[4], mx = -1e30f;
#pragma unroll
    for (int i = 0; i < 4; ++i) {
        int j = tid + i * 256;
        v[i] = (j < OUTD) ? Lr[j] : -1e30f;
        mx = fmaxf(mx, v[i]);
    }
#pragma unroll
    for (int off = 32; off; off >>= 1) mx = fmaxf(mx, __shfl_xor(mx, off, 64));
    if ((tid & 63) == 0) red[tid >> 6] = mx;
    __syncthreads();
    mx = fmaxf(fmaxf(red[0], red[1]), fmaxf(red[2], red[3]));
    float s = 0.f, ex[4];
#pragma unroll
    for (int i = 0; i < 4; ++i) {
        int j = tid + i * 256;
        ex[i] = (j < OUTD) ? expf(v[i] - mx) : 0.f;
        s += ex[i];
    }
#pragma unroll
    for (int off = 32; off; off >>= 1) s += __shfl_xor(s, off, 64);
    __syncthreads();
    if ((tid & 63) == 0) red[4 + (tid >> 6)] = s;
    __syncthreads();
    float inv = 1.f / (red[4] + red[5] + red[6] + red[7]);
#pragma unroll
    for (int i = 0; i < 4; ++i) {
        int j = tid + i * 256;
        if (j < OUTD) {
            float o = ex[i] * inv;
            if (bf) ((__hip_bfloat16*)out)[(long)b * OUTD + j] = __float2bfloat16(o);
            else    ((float*)out)[(long)b * OUTD + j] = o;
        }
    }
}

// =====================================================================
extern "C" void kernel_launch(void* const* d_in, const int* in_sizes, int n_in,
                              void* d_out, int out_size, void* d_ws, size_t ws_size,
                              hipStream_t stream) {
    const void* images = d_in[0];
    const int*  ei     = (const int*)d_in[1];
    const unsigned short* tag = (const unsigned short*)d_in[9];  // ln1_g (all ones)
    int E0 = in_sizes[1] / 2;

    char* p = (char*)d_ws;
    auto alloc = [&](size_t bytes) { char* r = p; p += (bytes + 255) & ~(size_t)255; return r; };
    float*          resid  = (float*)alloc((size_t)MROWS * HID * 4);       // 12.8 MB
    float*          hbuf   = (float*)alloc((size_t)MROWS * HID * 4);       // 12.8 MB
    __hip_bfloat16* xb     = (__hip_bfloat16*)alloc((size_t)MROWS * HID * 2);
    __hip_bfloat16* mid    = (__hip_bfloat16*)alloc((size_t)MROWS * MLPD * 2);
    float*          logits = (float*)alloc((size_t)BATCH * OUTD * 4);
    float*          pe     = (float*)alloc((size_t)NTOK * HID * 4);
    float*          adj    = (float*)alloc((size_t)NTOK * NTOK * 4);
    int*            nbrI   = (int*)alloc((size_t)NTOK * MAXDEG * 4);
    float*          nbrW   = (float*)alloc((size_t)NTOK * MAXDEG * 4);
    int*            degp   = (int*)alloc((size_t)NTOK * 4);
    __hip_bfloat16* smallp = (__hip_bfloat16*)alloc((size_t)SP_TOTAL * 2);
    __hip_bfloat16* wmapT  = (__hip_bfloat16*)alloc((size_t)KPATCH * HID * 2);
    __hip_bfloat16* wgatT  = (__hip_bfloat16*)alloc((size_t)NBLK * HID * HID * 2);
    __hip_bfloat16* w1T    = (__hip_bfloat16*)alloc((size_t)NBLK * HID * MLPD * 2);
    __hip_bfloat16* w2T    = (__hip_bfloat16*)alloc((size_t)NBLK * HID * MLPD * 2);
    __hip_bfloat16* woutT  = (__hip_bfloat16*)alloc((size_t)HID * OUTD * 2);

    SmallSrc ss = { d_in[3], d_in[4], d_in[6], d_in[7], d_in[8], d_in[9], d_in[10],
                    d_in[11], d_in[12], d_in[14], d_in[16], d_in[18] };
    prep_kernel<<<51, 64, 0, stream>>>(ei, E0, adj, pe, nbrI, nbrW, degp);
    pack_params<<<(SP_TOTAL + 255) / 256, 256, 0, stream>>>(ss, tag, smallp);
    transpose2<<<832, 256, 0, stream>>>(d_in[2], d_in[5], d_in[13], d_in[15],
                                        d_in[17], tag, wmapT, wgatT, w1T, w2T, woutT);
    init_resid<<<MROWS, 256, 0, stream>>>(smallp, pe, resid);
    patch_gemm128<<<dim3(MPATCH / 128, 2, 4), 256, 0, stream>>>(images, wmapT, tag, resid);

    for (int l = 0; l < NBLK; ++l) {
        ln_kernel<<<MROWS / 4, 256, 0, stream>>>(resid, smallp + OFF_LN1G + l * HID,
                                                 smallp + OFF_LN1B + l * HID, xb);
        gemm128<0><<<dim3(MROWS / 128, HID / 128), 256, 0, stream>>>(
            xb, wgatT + l * HID * HID, nullptr, hbuf, nullptr, MROWS, HID, HID);
        gat_kernel2<<<BATCH, 256, 0, stream>>>(hbuf, adj, nbrI, nbrW, degp,
                                               smallp, l, resid);
        ln_kernel<<<MROWS / 4, 256, 0, stream>>>(resid, smallp + OFF_LN2G + l * HID,
                                                 smallp + OFF_LN2B + l * HID, xb);
        gemm128<2><<<dim3(MROWS / 128, MLPD / 128), 256, 0, stream>>>(
            xb, w1T + l * HID * MLPD, smallp + OFF_B1 + l * MLPD, nullptr, mid,
            MROWS, MLPD, HID);
        gemm128<3><<<dim3(MROWS / 128, HID / 128), 256, 0, stream>>>(
            mid, w2T + l * HID * MLPD, smallp + OFF_B2 + l * HID, resid, nullptr,
            MROWS, HID, MLPD);
    }

    extract_cls<<<BATCH, 256, 0, stream>>>(resid, xb);
    gemm128<1><<<dim3(BATCH / 128, (OUTD + 127) / 128), 256, 0, stream>>>(
        xb, woutT, smallp + OFF_BOUT, logits, nullptr, BATCH, OUTD, HID);
    softmax_kernel<<<BATCH, 256, 0, stream>>>(logits, tag, d_out);
}

// Round 4
// 848.792 us; speedup vs baseline: 1.0959x; 1.0959x over previous
//
#include <hip/hip_runtime.h>
#include <hip/hip_bf16.h>

// ---------------- problem constants ----------------
#define BATCH   256
#define NTOK    50          // 49 patches + CLS
#define NPATCH  49
#define HID     256
#define HEADS   8
#define DH      32
#define NBLK    4
#define MLPD    1024
#define OUTD    1000
#define KPATCH  3072        // 3*32*32
#define MROWS   (BATCH*NTOK)     // 12800
#define MPATCH  (BATCH*NPATCH)   // 12544
#define MAXDEG  12               // max in-degree for t>=1 (8-neigh + self)

typedef __attribute__((ext_vector_type(4))) float  floatx4;
typedef __attribute__((ext_vector_type(8))) __bf16 bf16x8;
typedef __attribute__((ext_vector_type(4))) int    int4v;
typedef __attribute__((ext_vector_type(4))) short  short4v;

// Runtime input-dtype detection: ln1_g is all-ones. First 16-bit word is
// 0x3F80 iff the float inputs are bf16; fp32 gives 0x0000 (low mantissa).
// (Round-2 FETCH_SIZE ~154MB == fp32 images => this variant is fp32.)
__device__ __forceinline__ bool tag_is_bf16(const unsigned short* tag) {
    return tag[0] == 0x3F80u;
}
__device__ __forceinline__ float ldf(const void* p, long i, bool bf) {
    return bf ? __bfloat162float(((const __hip_bfloat16*)p)[i])
              : ((const float*)p)[i];
}

// fast erf-based GELU: Abramowitz-Stegun 7.1.26, |err| <= 1.5e-7 (abs).
__device__ __forceinline__ float fast_gelu(float u) {
    float s  = u * 0.70710678118654752f;
    float ax = fabsf(s);
    float t  = 1.f / (1.f + 0.3275911f * ax);
    float p  = fmaf(1.061405429f, t, -1.453152027f);
    p = fmaf(p, t, 1.421413741f);
    p = fmaf(p, t, -0.284496736f);
    p = fmaf(p, t, 0.254829592f);
    p *= t;
    float er = copysignf(1.f - p * __expf(-s * s), s);
    return 0.5f * u * (1.f + er);
}

// packed small-param layout (bf16 canonical), offsets in elements
#define OFF_BMAP 0
#define OFF_CLS  256
#define OFF_ASRC 512
#define OFF_ADST 1536
#define OFF_BGAT 2560
#define OFF_LN1G 3584
#define OFF_LN1B 4608
#define OFF_LN2G 5632
#define OFF_LN2B 6656
#define OFF_B1   7680
#define OFF_B2   11776
#define OFF_BOUT 12800
#define SP_TOTAL 13800

struct SmallSrc {
    const void *bmap, *cls, *asrc, *adst, *bgat, *ln1g, *ln1b, *ln2g, *ln2b, *b1, *b2, *bout;
};

__global__ void pack_params(SmallSrc s, const unsigned short* tag,
                            __hip_bfloat16* __restrict__ sp) {
    bool bf = tag_is_bf16(tag);
    int idx = blockIdx.x * 256 + threadIdx.x;
    if (idx >= SP_TOTAL) return;
    const void* src; long off;
    if      (idx < OFF_CLS)  { src = s.bmap; off = idx; }
    else if (idx < OFF_ASRC) { src = s.cls;  off = idx - OFF_CLS; }
    else if (idx < OFF_ADST) { src = s.asrc; off = idx - OFF_ASRC; }
    else if (idx < OFF_BGAT) { src = s.adst; off = idx - OFF_ADST; }
    else if (idx < OFF_LN1G) { src = s.bgat; off = idx - OFF_BGAT; }
    else if (idx < OFF_LN1B) { src = s.ln1g; off = idx - OFF_LN1G; }
    else if (idx < OFF_LN2G) { src = s.ln1b; off = idx - OFF_LN1B; }
    else if (idx < OFF_LN2B) { src = s.ln2g; off = idx - OFF_LN2G; }
    else if (idx < OFF_B1)   { src = s.ln2b; off = idx - OFF_LN2B; }
    else if (idx < OFF_B2)   { src = s.b1;   off = idx - OFF_B1; }
    else if (idx < OFF_BOUT) { src = s.b2;   off = idx - OFF_B2; }
    else                     { src = s.bout; off = idx - OFF_BOUT; }
    sp[idx] = __float2bfloat16(ldf(src, off, bf));
}

// =====================================================================
// prep: block 0 builds dense adjacency (counts + self loops) AND the
// per-target sparse neighbor lists; blocks 1..50 build the pos-emb table.
// =====================================================================
__global__ void prep_kernel(const int* __restrict__ ei, int E0,
                            float* __restrict__ adj, float* __restrict__ pe,
                            int* __restrict__ nbrI, float* __restrict__ nbrW,
                            int* __restrict__ deg) {
    int tid = threadIdx.x;
    if (blockIdx.x == 0) {
        for (int i = tid; i < NTOK * NTOK; i += 64) adj[i] = 0.f;
        __syncthreads();
        bool is64 = (ei[1] == 0);   // int64 little-endian high word
        for (int e = tid; e < E0; e += 64) {
            int s, d;
            if (is64) { s = ei[2 * e]; d = ei[2 * (E0 + e)]; }
            else      { s = ei[e];     d = ei[E0 + e]; }
            if ((unsigned)s < NTOK && (unsigned)d < NTOK)
                atomicAdd(&adj[d * NTOK + s], 1.f);
        }
        if (tid < NTOK) atomicAdd(&adj[tid * NTOK + tid], 1.f);  // self loops
        __syncthreads();
        if (tid > 0 && tid < NTOK) {            // t>=1 sparse in-lists
            int d = 0;
            for (int s = 0; s < NTOK; ++s) {
                float c = adj[tid * NTOK + s];
                if (c > 0.f && d < MAXDEG) { nbrI[tid * MAXDEG + d] = s;
                                             nbrW[tid * MAXDEG + d] = c; ++d; }
            }
            deg[tid] = d;
        }
        if (tid == 0) deg[0] = 0;               // t=0 handled full-width
    } else {
        int t = blockIdx.x - 1;
        for (int j = tid; j < HID; j += 64) {
            float jeff = (float)(j & ~1);
            float ang = (float)t / powf(10000.f, jeff / (float)HID);
            pe[t * HID + j] = ((j & 1) == 0) ? sinf(ang) : cosf(ang);
        }
    }
}

// =====================================================================
// LDS-tiled transpose of all weights to [N][K] canonical bf16.
// =====================================================================
__global__ __launch_bounds__(256) void transpose2(
    const void* __restrict__ Wmap, const void* __restrict__ Wgat,
    const void* __restrict__ W1,   const void* __restrict__ W2,
    const void* __restrict__ Wout, const unsigned short* tag,
    __hip_bfloat16* __restrict__ wmapT, __hip_bfloat16* __restrict__ wgatT,
    __hip_bfloat16* __restrict__ w1T,   __hip_bfloat16* __restrict__ w2T,
    __hip_bfloat16* __restrict__ woutT) {
    __shared__ __hip_bfloat16 tl[64][65];
    bool bf = tag_is_bf16(tag);
    int b = blockIdx.x;
    const void* src; __hip_bfloat16* dst; int R, C, tR; long so, dofs;
    if (b < 192)      { src = Wmap; dst = wmapT; R = 3072; C = 256;  tR = 48;
                        so = 0; dofs = 0; }
    else if (b < 256) { int ti = b - 192, l = ti >> 4; b = ti & 15;
                        src = Wgat; dst = wgatT; R = 256; C = 256; tR = 4;
                        so = (long)l * 65536; dofs = so; goto tiled; }
    else if (b < 512) { int ti = b - 256, l = ti >> 6; b = ti & 63;
                        src = W1; dst = w1T; R = 256; C = 1024; tR = 4;
                        so = (long)l * 262144; dofs = so; goto tiled; }
    else if (b < 768) { int ti = b - 512, l = ti >> 6; b = ti & 63;
                        src = W2; dst = w2T; R = 1024; C = 256; tR = 16;
                        so = (long)l * 262144; dofs = so; goto tiled; }
    else              { b -= 768; src = Wout; dst = woutT; R = 256; C = 1000;
                        tR = 4; so = 0; dofs = 0; }
tiled:
    int r0 = (b % tR) * 64, c0 = (b / tR) * 64;
    int tx = threadIdx.x & 63, ty = threadIdx.x >> 6;
#pragma unroll
    for (int j = 0; j < 16; ++j) {
        int rr = ty + 4 * j;
        float v = (c0 + tx < C) ? ldf(src, so + (long)(r0 + rr) * C + c0 + tx, bf) : 0.f;
        tl[rr][tx] = __float2bfloat16(v);
    }
    __syncthreads();
#pragma unroll
    for (int j = 0; j < 16; ++j) {
        int i2 = ty + 4 * j;
        if (c0 + i2 < C)
            dst[dofs + (long)(c0 + i2) * R + r0 + tx] = tl[tx][i2];
    }
}

// =====================================================================
// init resid with bias + positional emb (+ cls row), float4 stores.
// Runs BEFORE the split-K patch GEMM which atomically accumulates.
// =====================================================================
__global__ void init_resid(const __hip_bfloat16* __restrict__ sp,
                           const float* __restrict__ pe, float* __restrict__ resid) {
    int idx = blockIdx.x * 256 + threadIdx.x;   // < MROWS*HID/4
    int row = idx >> 6, c4 = (idx & 63) * 4, t = row % NTOK;
    floatx4 o;
#pragma unroll
    for (int i = 0; i < 4; ++i) {
        int c = c4 + i;
        o[i] = (t == 0) ? __bfloat162float(sp[OFF_CLS + c]) + pe[c]
                        : __bfloat162float(sp[OFF_BMAP + c]) + pe[t * HID + c];
    }
    ((floatx4*)resid)[idx] = o;
}

// =====================================================================
// 64x64 MFMA GEMM: C[M,N] = A[M,K] * BT[N,K]^T  (bf16 in, fp32 acc)
// 4 waves in 2x2, each wave 32x32 (2x2 of 16x16x32 MFMA). BK=32.
// LDS [64][32]: writes = lane-contiguous 16B, frag reads = 1KB permutation
// -> 0 bank conflicts. Register prefetch. 8 KB LDS -> high occupancy.
// MODE 0: outF=acc; 2: outB=bf16(gelu(acc+bias)); 3: outF+=acc+bias.
// =====================================================================
template<int MODE>
__global__ __launch_bounds__(256) void gemm64(
    const __hip_bfloat16* __restrict__ A, const __hip_bfloat16* __restrict__ BT,
    const __hip_bfloat16* __restrict__ bias,
    float* __restrict__ outF, __hip_bfloat16* __restrict__ outB,
    int M, int N, int K) {
    __shared__ short As[64][32];
    __shared__ short Bs[64][32];
    int tid = threadIdx.x;
    int m0 = blockIdx.x * 64, n0 = blockIdx.y * 64;
    int lr = tid >> 2, lc = (tid & 3) * 8;
    int lane = tid & 63, wave = tid >> 6;
    int wm = (wave >> 1) * 32, wn = (wave & 1) * 32;
    int q = lane >> 4, r = lane & 15, q8 = q * 8;
    const short* Ag = (const short*)A;
    const short* Bg = (const short*)BT;
    long a0 = (long)(m0 + lr) * K + lc;
    int bn = n0 + lr;
    long b0 = (long)bn * K + lc;
    bool v0 = bn < N;
    floatx4 acc[2][2];
#pragma unroll
    for (int i = 0; i < 2; ++i)
#pragma unroll
        for (int j = 0; j < 2; ++j) acc[i][j] = floatx4{0.f, 0.f, 0.f, 0.f};
    int4v za = {0, 0, 0, 0};
    int4v av = *(const int4v*)(Ag + a0);
    int4v bv = v0 ? *(const int4v*)(Bg + b0) : za;
    int nk = K >> 5;
    for (int kt = 0; kt < nk; ++kt) {
        __syncthreads();
        *(int4v*)&As[lr][lc] = av;
        *(int4v*)&Bs[lr][lc] = bv;
        __syncthreads();
        if (kt + 1 < nk) {
            long o = (long)(kt + 1) * 32;
            av = *(const int4v*)(Ag + a0 + o);
            bv = v0 ? *(const int4v*)(Bg + b0 + o) : za;
        }
        bf16x8 af[2], bfv[2];
#pragma unroll
        for (int i = 0; i < 2; ++i) af[i]  = *(const bf16x8*)&As[wm + 16 * i + r][q8];
#pragma unroll
        for (int j = 0; j < 2; ++j) bfv[j] = *(const bf16x8*)&Bs[wn + 16 * j + r][q8];
#pragma unroll
        for (int i = 0; i < 2; ++i)
#pragma unroll
            for (int j = 0; j < 2; ++j)
                acc[i][j] = __builtin_amdgcn_mfma_f32_16x16x32_bf16(af[i], bfv[j], acc[i][j], 0, 0, 0);
    }
    // epilogue: C/D layout col = lane&15, row = quad*4 + reg  [m89-verified]
#pragma unroll
    for (int j = 0; j < 2; ++j) {
        int col = n0 + wn + 16 * j + r;
        if (col >= N) continue;
        float bvv = (MODE != 0) ? __bfloat162float(bias[col]) : 0.f;
#pragma unroll
        for (int i = 0; i < 2; ++i) {
#pragma unroll
            for (int reg = 0; reg < 4; ++reg) {
                int row = m0 + wm + 16 * i + q * 4 + reg;
                float v = acc[i][j][reg];
                long oi = (long)row * N + col;
                if (MODE == 0) outF[oi] = v;
                if (MODE == 2) outB[oi] = __float2bfloat16(fast_gelu(v + bvv));
                if (MODE == 3) outF[oi] += v + bvv;
            }
        }
    }
}

// =====================================================================
// Head GEMM: logits[256,1000] = resid_cls[256,256] * WoutT^T + bout.
// A-loader reads CLS rows straight from fp32 resid (stride NTOK*HID),
// fusing extract_cls. M=256, K=256 fixed.
// =====================================================================
__global__ __launch_bounds__(256) void head_gemm(
    const float* __restrict__ resid, const __hip_bfloat16* __restrict__ BT,
    const __hip_bfloat16* __restrict__ bias, float* __restrict__ logits, int N) {
    __shared__ short As[64][32];
    __shared__ short Bs[64][32];
    int tid = threadIdx.x;
    int m0 = blockIdx.x * 64, n0 = blockIdx.y * 64;
    int lr = tid >> 2, lc = (tid & 3) * 8;
    int lane = tid & 63, wave = tid >> 6;
    int wm = (wave >> 1) * 32, wn = (wave & 1) * 32;
    int q = lane >> 4, r = lane & 15, q8 = q * 8;
    const short* Bg = (const short*)BT;
    long a0 = (long)(m0 + lr) * (NTOK * HID) + lc;   // CLS row of batch m0+lr
    int bn = n0 + lr;
    long b0 = (long)bn * HID + lc;
    bool v0 = bn < N;
    floatx4 acc[2][2];
#pragma unroll
    for (int i = 0; i < 2; ++i)
#pragma unroll
        for (int j = 0; j < 2; ++j) acc[i][j] = floatx4{0.f, 0.f, 0.f, 0.f};
    int4v za = {0, 0, 0, 0};
    auto loadA = [&](int k0) -> bf16x8 {
        floatx4 f0 = *(const floatx4*)(resid + a0 + k0);
        floatx4 f1 = *(const floatx4*)(resid + a0 + k0 + 4);
        union { bf16x8 v; __hip_bfloat16 h[8]; } u;
#pragma unroll
        for (int i = 0; i < 4; ++i) { u.h[i] = __float2bfloat16(f0[i]);
                                      u.h[4 + i] = __float2bfloat16(f1[i]); }
        return u.v;
    };
    bf16x8 av = loadA(0);
    int4v bv = v0 ? *(const int4v*)(Bg + b0) : za;
    for (int kt = 0; kt < 8; ++kt) {        // K = 256
        __syncthreads();
        *(bf16x8*)&As[lr][lc] = av;
        *(int4v*)&Bs[lr][lc] = bv;
        __syncthreads();
        if (kt < 7) {
            av = loadA((kt + 1) * 32);
            bv = v0 ? *(const int4v*)(Bg + b0 + (kt + 1) * 32) : za;
        }
        bf16x8 af[2], bfv[2];
#pragma unroll
        for (int i = 0; i < 2; ++i) af[i]  = *(const bf16x8*)&As[wm + 16 * i + r][q8];
#pragma unroll
        for (int j = 0; j < 2; ++j) bfv[j] = *(const bf16x8*)&Bs[wn + 16 * j + r][q8];
#pragma unroll
        for (int i = 0; i < 2; ++i)
#pragma unroll
            for (int j = 0; j < 2; ++j)
                acc[i][j] = __builtin_amdgcn_mfma_f32_16x16x32_bf16(af[i], bfv[j], acc[i][j], 0, 0, 0);
    }
#pragma unroll
    for (int j = 0; j < 2; ++j) {
        int col = n0 + wn + 16 * j + r;
        if (col >= N) continue;
        float bvv = __bfloat162float(bias[col]);
#pragma unroll
        for (int i = 0; i < 2; ++i)
#pragma unroll
            for (int reg = 0; reg < 4; ++reg) {
                int row = m0 + wm + 16 * i + q * 4 + reg;
                logits[(long)row * N + col] = acc[i][j][reg] + bvv;
            }
    }
}

// =====================================================================
// Patch-embed GEMM, 128x128 tile + split-K (8 chunks of 384).
// Patchify fused in the A loader (dtype-branched). AtomicAdds into resid
// (pre-initialized with bias+pe by init_resid).
// =====================================================================
__global__ __launch_bounds__(256) void patch_gemm128(
    const void* __restrict__ img, const __hip_bfloat16* __restrict__ wmapT,
    const unsigned short* tag, float* __restrict__ resid) {
    __shared__ short As[128][32];
    __shared__ short Bs[128][32];
    bool bf = tag_is_bf16(tag);
    int tid = threadIdx.x;
    int m0 = blockIdx.x * 128, n0 = blockIdx.y * 128, kc = blockIdx.z;
    int lr = tid >> 2, lc = (tid & 3) * 8;
    int lane = tid & 63, wave = tid >> 6;
    int wm = (wave >> 1) * 64, wn = (wave & 1) * 64;
    int q = lane >> 4, r = lane & 15, q8 = q * 8;
    int mA = m0 + lr, mB = mA + 64;
    long baseA, baseB;
    { int pb = mA / 49, pp = mA % 49; baseA = (long)pb * 150528 + (pp / 7) * 7168 + (pp % 7) * 32; }
    { int pb = mB / 49, pp = mB % 49; baseB = (long)pb * 150528 + (pp / 7) * 7168 + (pp % 7) * 32; }
    const short* Bg = (const short*)wmapT;
    long b0 = (long)(n0 + lr) * KPATCH + kc * 384 + lc;
    long b1 = b0 + (long)64 * KPATCH;
    floatx4 acc[4][4];
#pragma unroll
    for (int i = 0; i < 4; ++i)
#pragma unroll
        for (int j = 0; j < 4; ++j) acc[i][j] = floatx4{0.f, 0.f, 0.f, 0.f};
    auto loadA = [&](long base, int ku) -> bf16x8 {
        long gofs = base + (ku >> 5) * 50176 + (ku & 31) * 224 + lc;
        if (bf) return *(const bf16x8*)(((const __bf16*)img) + gofs);
        const float* f = (const float*)img;
        floatx4 f0 = *(const floatx4*)(f + gofs);
        floatx4 f1 = *(const floatx4*)(f + gofs + 4);
        union { bf16x8 v; __hip_bfloat16 h[8]; } u;
#pragma unroll
        for (int j = 0; j < 4; ++j) { u.h[j] = __float2bfloat16(f0[j]);
                                      u.h[4 + j] = __float2bfloat16(f1[j]); }
        return u.v;
    };
    int ku0 = kc * 12;                      // 8 chunks x 12 k-tiles of 32
    bf16x8 avA = loadA(baseA, ku0), avB = loadA(baseB, ku0);
    int4v bvA = *(const int4v*)(Bg + b0), bvB = *(const int4v*)(Bg + b1);
    for (int kt = 0; kt < 12; ++kt) {
        __syncthreads();
        *(bf16x8*)&As[lr][lc] = avA; *(bf16x8*)&As[64 + lr][lc] = avB;
        *(int4v*)&Bs[lr][lc] = bvA;  *(int4v*)&Bs[64 + lr][lc] = bvB;
        __syncthreads();
        if (kt < 11) {
            avA = loadA(baseA, ku0 + kt + 1); avB = loadA(baseB, ku0 + kt + 1);
            long o = (long)(kt + 1) * 32;
            bvA = *(const int4v*)(Bg + b0 + o); bvB = *(const int4v*)(Bg + b1 + o);
        }
        bf16x8 af[4], bfv[4];
#pragma unroll
        for (int i = 0; i < 4; ++i) af[i]  = *(const bf16x8*)&As[wm + 16 * i + r][q8];
#pragma unroll
        for (int j = 0; j < 4; ++j) bfv[j] = *(const bf16x8*)&Bs[wn + 16 * j + r][q8];
#pragma unroll
        for (int i = 0; i < 4; ++i)
#pragma unroll
            for (int j = 0; j < 4; ++j)
                acc[i][j] = __builtin_amdgcn_mfma_f32_16x16x32_bf16(af[i], bfv[j], acc[i][j], 0, 0, 0);
    }
#pragma unroll
    for (int j = 0; j < 4; ++j) {
        int col = n0 + wn + 16 * j + r;    // always < 256
#pragma unroll
        for (int i = 0; i < 4; ++i) {
#pragma unroll
            for (int reg = 0; reg < 4; ++reg) {
                int row = m0 + wm + 16 * i + q * 4 + reg;
                int bb = row / 49, pp = row % 49;
                atomicAdd(&resid[((long)bb * NTOK + pp + 1) * HID + col], acc[i][j][reg]);
            }
        }
    }
}

// =====================================================================
// LayerNorm: one wave per row, float4 loads, fp32 in -> bf16 out
// =====================================================================
__global__ __launch_bounds__(256) void ln_kernel(
    const float* __restrict__ x, const __hip_bfloat16* __restrict__ g,
    const __hip_bfloat16* __restrict__ bta, __hip_bfloat16* __restrict__ y) {
    int row = blockIdx.x * 4 + (threadIdx.x >> 6);
    int lane = threadIdx.x & 63;
    floatx4 v = ((const floatx4*)(x + (long)row * HID))[lane];
    float s = v[0] + v[1] + v[2] + v[3];
#pragma unroll
    for (int off = 32; off; off >>= 1) s += __shfl_xor(s, off, 64);
    float mu = s * (1.f / HID);
    float d2 = 0.f;
#pragma unroll
    for (int i = 0; i < 4; ++i) { float d = v[i] - mu; d2 += d * d; }
#pragma unroll
    for (int off = 32; off; off >>= 1) d2 += __shfl_xor(d2, off, 64);
    float rstd = rsqrtf(d2 * (1.f / HID) + 1e-5f);
    union { short4v s4; __hip_bfloat16 h[4]; } o;
#pragma unroll
    for (int i = 0; i < 4; ++i) {
        int c = lane * 4 + i;
        float t = (v[i] - mu) * rstd * __bfloat162float(g[c]) + __bfloat162float(bta[c]);
        o.h[i] = __float2bfloat16(t);
    }
    ((short4v*)(y + (long)row * HID))[lane] = o.s4;
}

// =====================================================================
// GAT v2: one block per batch. Phase 1: stage h + per-node logits.
// Phase 2: all (t,head) alphas in parallel (sparse lists, t=0 full-width).
// Phase 3: barrier-free sparse aggregation, resid += out + bias.
// =====================================================================
__global__ __launch_bounds__(256) void gat_kernel2(
    const float* __restrict__ h, const float* __restrict__ adj,
    const int* __restrict__ nbrI, const float* __restrict__ nbrW,
    const int* __restrict__ deg,
    const __hip_bfloat16* __restrict__ sp, int l, float* __restrict__ resid) {
    __shared__ float hs[NTOK][HID];                 // 50 KB
    __shared__ float als[NTOK][HEADS], ald[NTOK][HEADS];
    __shared__ float alpha0[HEADS][NTOK];
    __shared__ float alphaC[HEADS][NTOK][MAXDEG];   // 19.2 KB
    __shared__ float attS[HID], attD[HID], bg[HID];
    __shared__ int   nI[NTOK][MAXDEG];
    __shared__ int   dgs[NTOK];
    int b = blockIdx.x, tid = threadIdx.x;
    const float* hb = h + (long)b * (NTOK * HID);
    for (int i = tid; i < NTOK * HID / 4; i += 256)
        ((floatx4*)hs)[i] = ((const floatx4*)hb)[i];
    attS[tid] = __bfloat162float(sp[OFF_ASRC + l * HID + tid]);
    attD[tid] = __bfloat162float(sp[OFF_ADST + l * HID + tid]);
    bg[tid]   = __bfloat162float(sp[OFF_BGAT + l * HID + tid]);
    for (int i = tid; i < NTOK * MAXDEG; i += 256) ((int*)nI)[i] = nbrI[i];
    if (tid < NTOK) dgs[tid] = deg[tid];
    __syncthreads();
    for (int pr = tid; pr < NTOK * HEADS; pr += 256) {   // node logits
        int s = pr >> 3, hh = pr & 7;
        float a1 = 0.f, a2 = 0.f;
#pragma unroll
        for (int d = 0; d < DH; ++d) {
            float hv = hs[s][hh * DH + d];
            a1 += hv * attS[hh * DH + d];
            a2 += hv * attD[hh * DH + d];
        }
        als[s][hh] = a1; ald[s][hh] = a2;
    }
    __syncthreads();
    for (int pr = tid; pr < NTOK * HEADS; pr += 256) {   // edge softmax
        int t = pr >> 3, hh = pr & 7;
        float aldt = ald[t][hh];
        if (t == 0) {
            float mx = -1e30f;
            for (int s = 0; s < NTOK; ++s) {
                float w = adj[s];
                if (w > 0.f) {
                    float e = als[s][hh] + aldt; e = (e > 0.f) ? e : 0.2f * e;
                    mx = fmaxf(mx, e);
                }
            }
            float sum = 0.f;
            for (int s = 0; s < NTOK; ++s) {
                float w = adj[s], v = 0.f;
                if (w > 0.f) {
                    float e = als[s][hh] + aldt; e = (e > 0.f) ? e : 0.2f * e;
                    v = w * expf(e - mx);
                }
                alpha0[hh][s] = v; sum += v;
            }
            float inv = 1.f / (sum + 1e-16f);
            for (int s = 0; s < NTOK; ++s) alpha0[hh][s] *= inv;
        } else {
            int d = dgs[t];
            float mx = -1e30f;
            for (int j = 0; j < d; ++j) {
                float e = als[nI[t][j]][hh] + aldt; e = (e > 0.f) ? e : 0.2f * e;
                mx = fmaxf(mx, e);
            }
            float sum = 0.f;
            for (int j = 0; j < d; ++j) {
                float e = als[nI[t][j]][hh] + aldt; e = (e > 0.f) ? e : 0.2f * e;
                float w = nbrW[t * MAXDEG + j] * expf(e - mx);
                alphaC[hh][t][j] = w; sum += w;
            }
            float inv = 1.f / (sum + 1e-16f);
            for (int j = 0; j < d; ++j) alphaC[hh][t][j] *= inv;
        }
    }
    __syncthreads();
    int hd = tid >> 5, ln32 = tid & 31, col = hd * DH + ln32;
    float* res = resid + (long)b * (NTOK * HID);
    float bgc = bg[col];
    {
        float acc = 0.f;
        for (int s = 0; s < NTOK; ++s) acc += alpha0[hd][s] * hs[s][col];
        res[col] += acc + bgc;
    }
    for (int t = 1; t < NTOK; ++t) {
        float acc = 0.f; int d = dgs[t];
        for (int j = 0; j < d; ++j) acc += alphaC[hd][t][j] * hs[nI[t][j]][col];
        res[t * HID + col] += acc + bgc;
    }
}

// =====================================================================
__global__ __launch_bounds__(256) void softmax_kernel(
    const float* __restrict__ logits, const unsigned short* tag, void* __restrict__ out) {
    __shared__ float red[8];
    bool bf = tag_is_bf16(tag);
    int b = blockIdx.x, tid = threadIdx.x;
    const float* Lr = logits + (long)b * OUTD;
    float v[4], mx = -1e30f;
#pragma unroll
    for (int i = 0; i < 4; ++i) {
        int j = tid + i * 256;
        v[i] = (j < OUTD) ? Lr[j] : -1e30f;
        mx = fmaxf(mx, v[i]);
    }
#pragma unroll
    for (int off = 32; off; off >>= 1) mx = fmaxf(mx, __shfl_xor(mx, off, 64));
    if ((tid & 63) == 0) red[tid >> 6] = mx;
    __syncthreads();
    mx = fmaxf(fmaxf(red[0], red[1]), fmaxf(red[2], red[3]));
    float s = 0.f, ex[4];
#pragma unroll
    for (int i = 0; i < 4; ++i) {
        int j = tid + i * 256;
        ex[i] = (j < OUTD) ? expf(v[i] - mx) : 0.f;
        s += ex[i];
    }
#pragma unroll
    for (int off = 32; off; off >>= 1) s += __shfl_xor(s, off, 64);
    __syncthreads();
    if ((tid & 63) == 0) red[4 + (tid >> 6)] = s;
    __syncthreads();
    float inv = 1.f / (red[4] + red[5] + red[6] + red[7]);
#pragma unroll
    for (int i = 0; i < 4; ++i) {
        int j = tid + i * 256;
        if (j < OUTD) {
            float o = ex[i] * inv;
            if (bf) ((__hip_bfloat16*)out)[(long)b * OUTD + j] = __float2bfloat16(o);
            else    ((float*)out)[(long)b * OUTD + j] = o;
        }
    }
}

// =====================================================================
extern "C" void kernel_launch(void* const* d_in, const int* in_sizes, int n_in,
                              void* d_out, int out_size, void* d_ws, size_t ws_size,
                              hipStream_t stream) {
    const void* images = d_in[0];
    const int*  ei     = (const int*)d_in[1];
    const unsigned short* tag = (const unsigned short*)d_in[9];  // ln1_g (all ones)
    int E0 = in_sizes[1] / 2;

    char* p = (char*)d_ws;
    auto alloc = [&](size_t bytes) { char* r = p; p += (bytes + 255) & ~(size_t)255; return r; };
    float*          resid  = (float*)alloc((size_t)MROWS * HID * 4);
    float*          hbuf   = (float*)alloc((size_t)MROWS * HID * 4);
    __hip_bfloat16* xb     = (__hip_bfloat16*)alloc((size_t)MROWS * HID * 2);
    __hip_bfloat16* mid    = (__hip_bfloat16*)alloc((size_t)MROWS * MLPD * 2);
    float*          logits = (float*)alloc((size_t)BATCH * OUTD * 4);
    float*          pe     = (float*)alloc((size_t)NTOK * HID * 4);
    float*          adj    = (float*)alloc((size_t)NTOK * NTOK * 4);
    int*            nbrI   = (int*)alloc((size_t)NTOK * MAXDEG * 4);
    float*          nbrW   = (float*)alloc((size_t)NTOK * MAXDEG * 4);
    int*            degp   = (int*)alloc((size_t)NTOK * 4);
    __hip_bfloat16* smallp = (__hip_bfloat16*)alloc((size_t)SP_TOTAL * 2);
    __hip_bfloat16* wmapT  = (__hip_bfloat16*)alloc((size_t)KPATCH * HID * 2);
    __hip_bfloat16* wgatT  = (__hip_bfloat16*)alloc((size_t)NBLK * HID * HID * 2);
    __hip_bfloat16* w1T    = (__hip_bfloat16*)alloc((size_t)NBLK * HID * MLPD * 2);
    __hip_bfloat16* w2T    = (__hip_bfloat16*)alloc((size_t)NBLK * HID * MLPD * 2);
    __hip_bfloat16* woutT  = (__hip_bfloat16*)alloc((size_t)HID * OUTD * 2);

    SmallSrc ss = { d_in[3], d_in[4], d_in[6], d_in[7], d_in[8], d_in[9], d_in[10],
                    d_in[11], d_in[12], d_in[14], d_in[16], d_in[18] };
    prep_kernel<<<51, 64, 0, stream>>>(ei, E0, adj, pe, nbrI, nbrW, degp);
    pack_params<<<(SP_TOTAL + 255) / 256, 256, 0, stream>>>(ss, tag, smallp);
    transpose2<<<832, 256, 0, stream>>>(d_in[2], d_in[5], d_in[13], d_in[15],
                                        d_in[17], tag, wmapT, wgatT, w1T, w2T, woutT);
    init_resid<<<MROWS * HID / 1024, 256, 0, stream>>>(smallp, pe, resid);
    patch_gemm128<<<dim3(MPATCH / 128, 2, 8), 256, 0, stream>>>(images, wmapT, tag, resid);

    for (int l = 0; l < NBLK; ++l) {
        ln_kernel<<<MROWS / 4, 256, 0, stream>>>(resid, smallp + OFF_LN1G + l * HID,
                                                 smallp + OFF_LN1B + l * HID, xb);
        gemm64<0><<<dim3(MROWS / 64, HID / 64), 256, 0, stream>>>(
            xb, wgatT + l * HID * HID, nullptr, hbuf, nullptr, MROWS, HID, HID);
        gat_kernel2<<<BATCH, 256, 0, stream>>>(hbuf, adj, nbrI, nbrW, degp,
                                               smallp, l, resid);
        ln_kernel<<<MROWS / 4, 256, 0, stream>>>(resid, smallp + OFF_LN2G + l * HID,
                                                 smallp + OFF_LN2B + l * HID, xb);
        gemm64<2><<<dim3(MROWS / 64, MLPD / 64), 256, 0, stream>>>(
            xb, w1T + l * HID * MLPD, smallp + OFF_B1 + l * MLPD, nullptr, mid,
            MROWS, MLPD, HID);
        gemm64<3><<<dim3(MROWS / 64, HID / 64), 256, 0, stream>>>(
            mid, w2T + l * HID * MLPD, smallp + OFF_B2 + l * HID, resid, nullptr,
            MROWS, HID, MLPD);
    }

    head_gemm<<<dim3(BATCH / 64, (OUTD + 63) / 64), 256, 0, stream>>>(
        resid, woutT, smallp + OFF_BOUT, logits, OUTD);
    softmax_kernel<<<BATCH, 256, 0, stream>>>(logits, tag, d_out);
}